// Round 7
// baseline (491.190 us; speedup 1.0000x reference)
//
#include <hip/hip_runtime.h>

#define NPTS 16384
#define DH 256
#define PH 4096
#define D2 512

typedef _Float16 f16;
typedef _Float16 f16x4 __attribute__((ext_vector_type(4)));
typedef _Float16 f16x8 __attribute__((ext_vector_type(8)));
typedef float f32x4 __attribute__((ext_vector_type(4)));

// Static device scratch (d_out is only 16 MB = real part; d_ws size unknown).
// All buffers fully rewritten before use each call (deterministic).
// Swizzle convention: within each 64-half (128 B) row chunk, physical 16B
// slot s holds logical slot s^(row&7). Pre-swizzled in GLOBAL layouts so a
// linear global_load_lds produces the swizzled LDS image (m173 pattern).
__device__ f16   g_eAtS[(size_t)D2 * NPTS];   // 16 MB: eA^T fp16, swizzled
__device__ f16   g_Tt[8][D2][2*PH];           // 64 MB: T partials [z][d][cs*PH+q]
__device__ f16   g_TsS[(size_t)D2 * 2*PH];    //  8 MB: T summed, [d][2q+cs] swizzled
__device__ float g_G[4][NPTS][D2];            // 128 MB: G K-split partials

__device__ __forceinline__ void gload16(const void* g, void* l) {
    __builtin_amdgcn_global_load_lds((const __attribute__((address_space(1))) void*)g,
                                     (__attribute__((address_space(3))) void*)l, 16, 0, 0);
}

// ---------------------------------------------------------------------------
// eA^T precompute, swizzled: g_eAtS[d][64c+8s+i] = eA[64c+8(s^(d&7))+i][d].
// Rows d<256 = cos(A col d), d>=256 = sin; (d+256)&7 == d&7.
// ---------------------------------------------------------------------------
__global__ __launch_bounds__(256) void ker_pre(const float* __restrict__ pts,
                                               const float* __restrict__ A) {
    const int dd = blockIdx.x;           // 0..255
    const int t  = threadIdx.x;          // 64-col chunk c = t
    const float a0 = A[dd], a1 = A[DH + dd], a2 = A[2*DH + dd];
    f16* rowc = &g_eAtS[(size_t)dd*NPTS + t*64];
    f16* rows = &g_eAtS[(size_t)(DH + dd)*NPTS + t*64];
    const int sx = dd & 7;
    #pragma unroll
    for (int s = 0; s < 8; ++s) {
        const int nb = t*64 + 8*(s ^ sx);
        f16x8 vc, vs;
        #pragma unroll
        for (int i = 0; i < 8; ++i) {
            const float* pr = pts + (size_t)(nb + i)*3;
            float sn, cs_; __sincosf(pr[0]*a0 + pr[1]*a1 + pr[2]*a2, &sn, &cs_);
            vc[i] = (f16)cs_; vs[i] = (f16)sn;
        }
        *(f16x8*)(rowc + 8*s) = vc;
        *(f16x8*)(rows + 8*s) = vs;
    }
}

// ---------------------------------------------------------------------------
// GEMM1: T = eB^T eA. Block 256M x 256N, BK=64 n. M = 128 q x {cos|sin}.
// Grid (32, 2, 8) = 512 blocks = 2/CU. 8 waves (2M x 4N), wave-tile 128x64
// (FLOP/LDS-byte 42.7 vs 32 at 64x64 -> lifts the LDS-read bound).
// A (eB) trig -> swizzled ds_write; B (eA^T) swizzled global_load_lds.
// ---------------------------------------------------------------------------
__global__ __launch_bounds__(512) void ker_T(const float* __restrict__ pts,
                                             const float* __restrict__ B) {
    const int q0 = blockIdx.x * 128;
    const int d0 = blockIdx.y * 256;
    const int ks = blockIdx.z;               // n range [ks*2048, +2048)
    const int t  = threadIdx.x;
    const int lane = t & 63, wid = t >> 6;
    const int wm = wid >> 2, wn = wid & 3;
    const int l7 = lane & 7;

    __shared__ f16 Al[256][64];   // rows 0..127 cos q, 128..255 sin q (swizzled)
    __shared__ f16 Bl[256][64];   // [d][n] (swizzled)

    f32x4 acc[8][4];
    #pragma unroll
    for (int a = 0; a < 8; ++a)
        #pragma unroll
        for (int bq = 0; bq < 4; ++bq) acc[a][bq] = (f32x4){0.f,0.f,0.f,0.f};

    // A-trig map: thread owns q-row qq = t>>2, n-chunk (t&3)*16 (16 sincos/iter)
    const int qq  = t >> 2;
    const int nch = (t & 3) * 16;
    const int s0  = (t & 3) * 2;       // first logical slot of this thread
    const int sx  = qq & 7;
    const float b0 = B[q0+qq], b1 = B[PH+q0+qq], b2 = B[2*PH+q0+qq];
    // B gload: wave covers rows 32*wid..+31 in 4 gloads of 8 rows
    const size_t bsrc0 = (size_t)(d0 + 32*wid + (lane >> 3))*NPTS + 8*l7;
    // frag row bases
    const int ar = wm*128 + (lane & 15);
    const int br = wn*64  + (lane & 15);

    for (int c = 0; c < 32; ++c) {
        const int nb = ks*2048 + c*64;
        __syncthreads();   // previous tile's frag reads done
        // B stage: 4 x gload16 (issued first so latency hides under trig)
        #pragma unroll
        for (int i = 0; i < 4; ++i)
            gload16(&g_eAtS[0] + bsrc0 + (size_t)(8*i)*NPTS + (size_t)nb,
                    &Bl[32*wid + 8*i][0]);
        // A stage: 16 sincos -> 2 cos slots + 2 sin slots (XOR-swizzled)
        {
            const float* pb = pts + (size_t)(nb + nch)*3;
            f16x8 vc0, vc1, vs0, vs1;
            #pragma unroll
            for (int g = 0; g < 4; ++g) {
                const float4 Pa = *(const float4*)(pb + 12*g);
                const float4 Pb = *(const float4*)(pb + 12*g + 4);
                const float4 Pc = *(const float4*)(pb + 12*g + 8);
                const float xx[4] = {Pa.x, Pa.w, Pb.z, Pc.y};
                const float yy[4] = {Pa.y, Pb.x, Pb.w, Pc.z};
                const float zz[4] = {Pa.z, Pb.y, Pc.x, Pc.w};
                #pragma unroll
                for (int u = 0; u < 4; ++u) {
                    float sn, cs_;
                    __sincosf(xx[u]*b0 + yy[u]*b1 + zz[u]*b2, &sn, &cs_);
                    const int idx = 4*g + u;
                    if (idx < 8) { vc0[idx] = (f16)cs_; vs0[idx] = (f16)sn; }
                    else         { vc1[idx-8] = (f16)cs_; vs1[idx-8] = (f16)sn; }
                }
            }
            *(f16x8*)&Al[qq][((s0  ) ^ sx)*8]       = vc0;
            *(f16x8*)&Al[qq][((s0+1) ^ sx)*8]       = vc1;
            *(f16x8*)&Al[128 + qq][((s0  ) ^ sx)*8] = vs0;
            *(f16x8*)&Al[128 + qq][((s0+1) ^ sx)*8] = vs1;
        }
        __syncthreads();   // drains vmcnt+lgkmcnt (compiler-emitted)
        #pragma unroll
        for (int kk = 0; kk < 2; ++kk) {
            f16x8 af[8], bf[4];
            #pragma unroll
            for (int mf = 0; mf < 8; ++mf)
                af[mf] = *(const f16x8*)&Al[ar + mf*16][ ((((lane>>4) + 4*kk)) ^ l7) * 8 ];
            #pragma unroll
            for (int nf = 0; nf < 4; ++nf)
                bf[nf] = *(const f16x8*)&Bl[br + nf*16][ ((((lane>>4) + 4*kk)) ^ l7) * 8 ];
            #pragma unroll
            for (int mf = 0; mf < 8; ++mf)
                #pragma unroll
                for (int nf = 0; nf < 4; ++nf)
                    acc[mf][nf] = __builtin_amdgcn_mfma_f32_16x16x32_f16(
                        af[mf], bf[nf], acc[mf][nf], 0, 0, 0);
        }
    }
    // epilogue: wave wm=0 -> cos rows, wm=1 -> sin rows; D row=(l>>4)*4+j, col=l&15
    #pragma unroll
    for (int mf = 0; mf < 8; ++mf) {
        const int qrow = q0 + mf*16 + (lane >> 4)*4;
        #pragma unroll
        for (int nf = 0; nf < 4; ++nf) {
            const int d = d0 + wn*64 + nf*16 + (lane & 15);
            f16x4 v;
            #pragma unroll
            for (int j = 0; j < 4; ++j) v[j] = (f16)acc[mf][nf][j];
            *(f16x4*)&g_Tt[ks][d][(size_t)wm*PH + qrow] = v;
        }
    }
}

// ---------------------------------------------------------------------------
// Sum 8 T partials -> g_TsS, interleaved [d][2q+cs], swizzled per 64-chunk.
// ---------------------------------------------------------------------------
__global__ __launch_bounds__(256) void ker_tsum() {
    const int u  = blockIdx.x*256 + threadIdx.x;   // 2048 blocks
    const int d  = u >> 10;
    const int jj = u & 1023;
    const int c = jj >> 3, s = jj & 7;
    const int klb = 64*c + 8*(s ^ (d & 7));        // logical interleaved-k base
    const int q0_ = klb >> 1;
    float oc[4] = {0,0,0,0}, os[4] = {0,0,0,0};
    #pragma unroll
    for (int z = 0; z < 8; ++z) {
        const f16x4 a  = *(const f16x4*)&g_Tt[z][d][q0_];
        const f16x4 bs = *(const f16x4*)&g_Tt[z][d][PH + q0_];
        #pragma unroll
        for (int j = 0; j < 4; ++j) { oc[j] += (float)a[j]; os[j] += (float)bs[j]; }
    }
    f16x8 v;
    #pragma unroll
    for (int j = 0; j < 4; ++j) { v[2*j] = (f16)oc[j]; v[2*j+1] = (f16)os[j]; }
    *(f16x8*)&g_TsS[(size_t)d*(2*PH) + 64*c + 8*s] = v;
}

// ---------------------------------------------------------------------------
// GEMM2: G = eB T. Block 256M(n) x 256N(d), BK=64 interleaved k (=32 q x cs).
// Grid (64, 2, 4) = 512 blocks. Same wave/LDS geometry as ker_T.
// ---------------------------------------------------------------------------
__global__ __launch_bounds__(512) void ker_G(const float* __restrict__ pts,
                                             const float* __restrict__ B) {
    const int n0 = blockIdx.x * 256;
    const int d0 = blockIdx.y * 256;
    const int ks = blockIdx.z;               // q range [ks*1024, +1024)
    const int t  = threadIdx.x;
    const int lane = t & 63, wid = t >> 6;
    const int wm = wid >> 2, wn = wid & 3;
    const int l7 = lane & 7;

    __shared__ f16 Al[256][64];   // [n][ik] swizzled
    __shared__ f16 Bl[256][64];   // [d][ik] swizzled

    f32x4 acc[8][4];
    #pragma unroll
    for (int a = 0; a < 8; ++a)
        #pragma unroll
        for (int bq = 0; bq < 4; ++bq) acc[a][bq] = (f32x4){0.f,0.f,0.f,0.f};

    // A-trig map: thread owns n-row nn = t>>1, q-chunk (t&1)*16 (16 sincos/iter)
    const int nn    = t >> 1;
    const int qch   = (t & 1) * 16;
    const int sbase = (t & 1) * 4;
    const int sx    = nn & 7;
    const float px = pts[(size_t)(n0+nn)*3];
    const float py = pts[(size_t)(n0+nn)*3 + 1];
    const float pz = pts[(size_t)(n0+nn)*3 + 2];
    const size_t bsrc0 = (size_t)(d0 + 32*wid + (lane >> 3))*(2*PH) + 8*l7;
    const int ar = wm*128 + (lane & 15);
    const int br = wn*64  + (lane & 15);

    for (int c = 0; c < 32; ++c) {
        const int qk = ks*1024 + c*32;
        const int kb = 2*qk;
        __syncthreads();
        #pragma unroll
        for (int i = 0; i < 4; ++i)
            gload16(&g_TsS[0] + bsrc0 + (size_t)(8*i)*(2*PH) + (size_t)kb,
                    &Bl[32*wid + 8*i][0]);
        {   // A stage: 16 betas -> 4 interleaved (cos,sin) slots
            const int qg = qk + qch;
            #pragma unroll
            for (int g = 0; g < 4; ++g) {
                const float4 X = *(const float4*)&B[qg + 4*g];
                const float4 Y = *(const float4*)&B[PH + qg + 4*g];
                const float4 Z = *(const float4*)&B[2*PH + qg + 4*g];
                const float bx[4] = {X.x, X.y, X.z, X.w};
                const float by[4] = {Y.x, Y.y, Y.z, Y.w};
                const float bz[4] = {Z.x, Z.y, Z.z, Z.w};
                f16x8 vv;
                #pragma unroll
                for (int u = 0; u < 4; ++u) {
                    float sn, cs_;
                    __sincosf(px*bx[u] + py*by[u] + pz*bz[u], &sn, &cs_);
                    vv[2*u] = (f16)cs_; vv[2*u+1] = (f16)sn;
                }
                *(f16x8*)&Al[nn][((sbase + g) ^ sx)*8] = vv;
            }
        }
        __syncthreads();
        #pragma unroll
        for (int kk = 0; kk < 2; ++kk) {
            f16x8 af[8], bf[4];
            #pragma unroll
            for (int mf = 0; mf < 8; ++mf)
                af[mf] = *(const f16x8*)&Al[ar + mf*16][ ((((lane>>4) + 4*kk)) ^ l7) * 8 ];
            #pragma unroll
            for (int nf = 0; nf < 4; ++nf)
                bf[nf] = *(const f16x8*)&Bl[br + nf*16][ ((((lane>>4) + 4*kk)) ^ l7) * 8 ];
            #pragma unroll
            for (int mf = 0; mf < 8; ++mf)
                #pragma unroll
                for (int nf = 0; nf < 4; ++nf)
                    acc[mf][nf] = __builtin_amdgcn_mfma_f32_16x16x32_f16(
                        af[mf], bf[nf], acc[mf][nf], 0, 0, 0);
        }
    }
    // epilogue -> g_G[ks][n][d] fp32
    #pragma unroll
    for (int mf = 0; mf < 8; ++mf) {
        const int nbase = n0 + wm*128 + mf*16 + (lane >> 4)*4;
        #pragma unroll
        for (int nf = 0; nf < 4; ++nf) {
            const int d = d0 + wn*64 + nf*16 + (lane & 15);
            #pragma unroll
            for (int j = 0; j < 4; ++j)
                g_G[ks][nbase + j][d] = acc[mf][nf][j];
        }
    }
}

// ---------------------------------------------------------------------------
// Epilogue: Gc = (Gr+i*Gi)*conj(e^{i alpha}) (|e^{ia}|=1, divide==conj-mult;
// rotation preserves row norm -> scale = 16/||G row||). Output = REAL part.
// ---------------------------------------------------------------------------
__global__ __launch_bounds__(256) void ker_fin(const float* __restrict__ pts,
                                               const float* __restrict__ A,
                                               float* __restrict__ out) {
    const int n = blockIdx.x;
    const int k = threadIdx.x;  // 0..255
    const float p0 = pts[(size_t)n*3], p1 = pts[(size_t)n*3+1], p2 = pts[(size_t)n*3+2];
    const float alp = p0*A[k] + p1*A[DH + k] + p2*A[2*DH + k];
    float sa, ca; __sincosf(alp, &sa, &ca);
    const float Gr = g_G[0][n][k]      + g_G[1][n][k]      + g_G[2][n][k]      + g_G[3][n][k];
    const float Gi = g_G[0][n][DH + k] + g_G[1][n][DH + k] + g_G[2][n][DH + k] + g_G[3][n][DH + k];
    const float Re = Gr*ca + Gi*sa;
    float nr = Gr*Gr + Gi*Gi;
    #pragma unroll
    for (int off = 32; off > 0; off >>= 1) nr += __shfl_down(nr, off, 64);
    __shared__ float wsum[4];
    if ((k & 63) == 0) wsum[k >> 6] = nr;
    __syncthreads();
    const float total = wsum[0] + wsum[1] + wsum[2] + wsum[3];
    const float scale = 16.0f * rsqrtf(total);
    out[(size_t)n*DH + k] = Re * scale;
}

extern "C" void kernel_launch(void* const* d_in, const int* in_sizes, int n_in,
                              void* d_out, int out_size, void* d_ws, size_t ws_size,
                              hipStream_t stream) {
    const float* pts = (const float*)d_in[0];
    const float* A   = (const float*)d_in[1];
    const float* B   = (const float*)d_in[2];
    float* out = (float*)d_out;
    (void)d_ws; (void)ws_size; (void)out_size;

    ker_pre <<<256, 256, 0, stream>>>(pts, A);
    ker_T   <<<dim3(32, 2, 8), 512, 0, stream>>>(pts, B);
    ker_tsum<<<2048, 256, 0, stream>>>();
    ker_G   <<<dim3(64, 2, 4), 512, 0, stream>>>(pts, B);
    ker_fin <<<16384, 256, 0, stream>>>(pts, A, out);
}

// Round 8
// 390.058 us; speedup vs baseline: 1.2593x; 1.2593x over previous
//
#include <hip/hip_runtime.h>

#define NPTS 16384
#define DH 256
#define PH 4096
#define D2 512
#define LDA 40   // padded K-stride for trig-staged A tiles (ds_write side)

typedef _Float16 f16;
typedef _Float16 f16x4 __attribute__((ext_vector_type(4)));
typedef _Float16 f16x8 __attribute__((ext_vector_type(8)));
typedef float f32x4 __attribute__((ext_vector_type(4)));

// Static device scratch (d_out is only 16 MB = real part; d_ws size unknown).
// All buffers fully rewritten before use each call (deterministic).
__device__ f16   g_eAt[D2][NPTS];       // 16 MB: eA^T fp16 [d][n], linear
__device__ f16   g_Tt[4][D2][2*PH];     // 64 MB: T K-split partials [z][d][cs*PH+q]
__device__ f16   g_Ts[D2][2*PH];        //  8 MB: summed T^T [d][cs*PH+q]
__device__ float g_G[2][NPTS][D2];      // 64 MB: G K-split partials

__device__ __forceinline__ void gload16(const void* g, void* l) {
    __builtin_amdgcn_global_load_lds((const __attribute__((address_space(1))) void*)g,
                                     (__attribute__((address_space(3))) void*)l, 16, 0, 0);
}

// Fast native sincos: v_mul + v_sin_f32 / v_cos_f32 (NOT __sincosf ==
// precise __ocml_sincos_f32 with ~100-cycle range reduction -- that was
// the dominant cost of R4-R7's GEMM staging). |angle| < 20 rad here, well
// inside HW range; fp16 storage (2^-11) swamps native-trig error.
__device__ __forceinline__ void fsincos(float x, float* s, float* c) {
    *s = __sinf(x);
    *c = __cosf(x);
}

// ---------------------------------------------------------------------------
// eA^T precompute (linear): g_eAt[d][n]=cos(alpha), g_eAt[256+d][n]=sin.
// ---------------------------------------------------------------------------
__global__ __launch_bounds__(256) void ker_pre(const float* __restrict__ pts,
                                               const float* __restrict__ A) {
    const int dd = blockIdx.x;           // 0..255
    const int t  = threadIdx.x;          // 64-col chunk c = t
    const float a0 = A[dd], a1 = A[DH + dd], a2 = A[2*DH + dd];
    f16* rowc = &g_eAt[dd][t*64];
    f16* rows = &g_eAt[DH + dd][t*64];
    #pragma unroll
    for (int s = 0; s < 8; ++s) {
        const int nb = t*64 + 8*s;
        f16x8 vc, vs;
        #pragma unroll
        for (int i = 0; i < 8; ++i) {
            const float* pr = pts + (size_t)(nb + i)*3;
            float sn, cs_; fsincos(pr[0]*a0 + pr[1]*a1 + pr[2]*a2, &sn, &cs_);
            vc[i] = (f16)cs_; vs[i] = (f16)sn;
        }
        *(f16x8*)(rowc + 8*s) = vc;
        *(f16x8*)(rows + 8*s) = vs;
    }
}

// ---------------------------------------------------------------------------
// GEMM1: T = eB^T eA. Block: M=128 (64 q x {cos,sin}), N=256 d, BK=32 n.
// Grid (64, 2, 4) = 512 blocks. 512 thr, 8 waves (2M x 4N), wave-tile 64x64
// (acc=64 regs -> high occupancy; R7 showed 128-acc kills it).
// A (eB) trig -> ds_write (padded); B (eA^T) global_load_lds.
// ---------------------------------------------------------------------------
__global__ __launch_bounds__(512) void ker_T(const float* __restrict__ pts,
                                             const float* __restrict__ B) {
    const int q0 = blockIdx.x * 64;
    const int d0 = blockIdx.y * 256;
    const int ks = blockIdx.z;               // n range [ks*4096, +4096)
    const int t  = threadIdx.x;
    const int lane = t & 63, wid = t >> 6;
    const int wm = wid >> 2, wn = wid & 3;

    __shared__ f16 Al[128][LDA];   // [q.cs][n] padded (ds_write staging)
    __shared__ f16 Bl[256][32];    // [d][n] linear (gload_lds dest)

    f32x4 acc[4][4];
    #pragma unroll
    for (int a = 0; a < 4; ++a)
        #pragma unroll
        for (int bq = 0; bq < 4; ++bq) acc[a][bq] = (f32x4){0.f,0.f,0.f,0.f};

    // A-trig: qq = t>>3 (0..63), 4 n per iter at nn0=(t&7)*4
    const int qq  = t >> 3;
    const int nn0 = (t & 7) * 4;
    const float b0 = B[q0+qq], b1 = B[PH+q0+qq], b2 = B[2*PH+q0+qq];
    // B gload: wave rows 32*wid..; lane -> row + (lane>>2), 8-half slot lane&3
    const size_t bsrc0 = (size_t)(d0 + 32*wid + (lane >> 2))*NPTS + 8*(lane & 3);
    // frag coords
    const int mrow = wm*64 + (lane & 15);
    const int ncol = wn*64 + (lane & 15);
    const int kof  = (lane >> 4) * 8;

    for (int c = 0; c < 128; ++c) {
        const int nb = ks*4096 + c*32;
        __syncthreads();   // previous compute's LDS reads done
        // B stage first (latency hides under trig)
        gload16(&g_eAt[0][0] + bsrc0 + (size_t)nb,                   &Bl[32*wid][0]);
        gload16(&g_eAt[0][0] + bsrc0 + (size_t)16*NPTS + (size_t)nb, &Bl[32*wid + 16][0]);
        {   // A stage: 4 consecutive pts rows = 12 contiguous floats
            const float* pbase = pts + (size_t)(nb + nn0)*3;
            const float4 P0 = *(const float4*)(pbase);
            const float4 P1 = *(const float4*)(pbase + 4);
            const float4 P2 = *(const float4*)(pbase + 8);
            const float px[4] = {P0.x, P0.w, P1.z, P2.y};
            const float py[4] = {P0.y, P1.x, P1.w, P2.z};
            const float pz[4] = {P0.z, P1.y, P2.x, P2.w};
            f16x4 vc, vs;
            #pragma unroll
            for (int u = 0; u < 4; ++u) {
                float sn, cc; fsincos(px[u]*b0 + py[u]*b1 + pz[u]*b2, &sn, &cc);
                vc[u] = (f16)cc; vs[u] = (f16)sn;
            }
            *(f16x4*)&Al[qq][nn0]      = vc;
            *(f16x4*)&Al[64 + qq][nn0] = vs;
        }
        __syncthreads();   // drains vmcnt+lgkmcnt (compiler-emitted)
        f16x8 af[4], bf[4];
        #pragma unroll
        for (int mf = 0; mf < 4; ++mf) af[mf] = *(const f16x8*)&Al[mrow + mf*16][kof];
        #pragma unroll
        for (int nf = 0; nf < 4; ++nf) bf[nf] = *(const f16x8*)&Bl[ncol + nf*16][kof];
        #pragma unroll
        for (int mf = 0; mf < 4; ++mf)
            #pragma unroll
            for (int nf = 0; nf < 4; ++nf)
                acc[mf][nf] = __builtin_amdgcn_mfma_f32_16x16x32_f16(
                    af[mf], bf[nf], acc[mf][nf], 0, 0, 0);
    }
    // epilogue: wave wm: 0=cos rows, 1=sin rows; M-row = mf*16+(l>>4)*4+j -> q
    #pragma unroll
    for (int mf = 0; mf < 4; ++mf) {
        const int qrow = q0 + mf*16 + (lane >> 4)*4;
        #pragma unroll
        for (int nf = 0; nf < 4; ++nf) {
            const int d = d0 + wn*64 + nf*16 + (lane & 15);
            f16x4 v;
            #pragma unroll
            for (int j = 0; j < 4; ++j) v[j] = (f16)acc[mf][nf][j];
            *(f16x4*)&g_Tt[ks][d][(size_t)wm*PH + qrow] = v;
        }
    }
}

// ---------------------------------------------------------------------------
// Sum 4 T partials -> g_Ts fp16.
// ---------------------------------------------------------------------------
__global__ __launch_bounds__(256) void ker_tsum() {
    const size_t i = ((size_t)blockIdx.x*256 + threadIdx.x) * 8;
    float o[8] = {0,0,0,0,0,0,0,0};
    #pragma unroll
    for (int z = 0; z < 4; ++z) {
        const f16x8 v = *(const f16x8*)(&g_Tt[z][0][0] + i);
        #pragma unroll
        for (int j = 0; j < 8; ++j) o[j] += (float)v[j];
    }
    f16x8 r;
    #pragma unroll
    for (int j = 0; j < 8; ++j) r[j] = (f16)o[j];
    *(f16x8*)(&g_Ts[0][0] + i) = r;
}

// ---------------------------------------------------------------------------
// GEMM2: G = eB T. Block: M=128 n, N=256 d, 32 q per iter (K eff 64).
// Grid (128, 2, 2) = 512 blocks. 512 thr, 8 waves (2M x 4N), wave-tile 64x64.
// A (eB cos/sin) trig->ds_write; B (Ts cos/sin cols) global_load_lds.
// ---------------------------------------------------------------------------
__global__ __launch_bounds__(512) void ker_G(const float* __restrict__ pts,
                                             const float* __restrict__ B) {
    const int n0 = blockIdx.x * 128;
    const int d0 = blockIdx.y * 256;
    const int ks = blockIdx.z;               // q range [ks*2048, +2048)
    const int t  = threadIdx.x;
    const int lane = t & 63, wid = t >> 6;
    const int wm = wid >> 2, wn = wid & 3;

    __shared__ f16 Ac[128][LDA], As[128][LDA];   // eB cos/sin [n][q] padded
    __shared__ f16 Bc[256][32],  Bs[256][32];    // Ts cols    [d][q] linear

    f32x4 acc[4][4];
    #pragma unroll
    for (int a = 0; a < 4; ++a)
        #pragma unroll
        for (int bq = 0; bq < 4; ++bq) acc[a][bq] = (f32x4){0.f,0.f,0.f,0.f};

    // A-trig: nn = t>>2 (0..127) fixed pts row; 8 q per iter at qq0=(t&3)*8
    const int nn  = t >> 2;
    const int qq0 = (t & 3) * 8;
    const float px = pts[(size_t)(n0+nn)*3];
    const float py = pts[(size_t)(n0+nn)*3 + 1];
    const float pz = pts[(size_t)(n0+nn)*3 + 2];
    // B gload
    const size_t bsrc0 = (size_t)(d0 + 32*wid + (lane >> 2))*(2*PH) + 8*(lane & 3);
    const int mrow = wm*64 + (lane & 15);
    const int ncol = wn*64 + (lane & 15);
    const int kof  = (lane >> 4) * 8;

    for (int c = 0; c < 64; ++c) {
        const int qk = ks*2048 + c*32;
        __syncthreads();
        // B stage: 4 x gload16 (cos rows x2, sin rows x2)
        gload16(&g_Ts[0][0] + bsrc0 + (size_t)qk,                            &Bc[32*wid][0]);
        gload16(&g_Ts[0][0] + bsrc0 + (size_t)16*(2*PH) + (size_t)qk,        &Bc[32*wid + 16][0]);
        gload16(&g_Ts[0][0] + bsrc0 + (size_t)PH + (size_t)qk,               &Bs[32*wid][0]);
        gload16(&g_Ts[0][0] + bsrc0 + (size_t)(16*(2*PH) + PH) + (size_t)qk, &Bs[32*wid + 16][0]);
        {   // A stage: 8 betas for fixed n-row
            const int qg = qk + qq0;
            const float4 bx0 = *(const float4*)&B[qg];
            const float4 bx1 = *(const float4*)&B[qg + 4];
            const float4 by0 = *(const float4*)&B[PH + qg];
            const float4 by1 = *(const float4*)&B[PH + qg + 4];
            const float4 bz0 = *(const float4*)&B[2*PH + qg];
            const float4 bz1 = *(const float4*)&B[2*PH + qg + 4];
            const float bx[8] = {bx0.x,bx0.y,bx0.z,bx0.w, bx1.x,bx1.y,bx1.z,bx1.w};
            const float by[8] = {by0.x,by0.y,by0.z,by0.w, by1.x,by1.y,by1.z,by1.w};
            const float bz[8] = {bz0.x,bz0.y,bz0.z,bz0.w, bz1.x,bz1.y,bz1.z,bz1.w};
            f16x8 vc, vs;
            #pragma unroll
            for (int u = 0; u < 8; ++u) {
                float sn, cc; fsincos(px*bx[u] + py*by[u] + pz*bz[u], &sn, &cc);
                vc[u] = (f16)cc; vs[u] = (f16)sn;
            }
            *(f16x8*)&Ac[nn][qq0] = vc;
            *(f16x8*)&As[nn][qq0] = vs;
        }
        __syncthreads();
        f16x8 a1[4], a2[4], b1[4], b2[4];
        #pragma unroll
        for (int mf = 0; mf < 4; ++mf) {
            a1[mf] = *(const f16x8*)&Ac[mrow + mf*16][kof];
            a2[mf] = *(const f16x8*)&As[mrow + mf*16][kof];
        }
        #pragma unroll
        for (int nf = 0; nf < 4; ++nf) {
            b1[nf] = *(const f16x8*)&Bc[ncol + nf*16][kof];
            b2[nf] = *(const f16x8*)&Bs[ncol + nf*16][kof];
        }
        #pragma unroll
        for (int mf = 0; mf < 4; ++mf)
            #pragma unroll
            for (int nf = 0; nf < 4; ++nf) {
                acc[mf][nf] = __builtin_amdgcn_mfma_f32_16x16x32_f16(
                    a1[mf], b1[nf], acc[mf][nf], 0, 0, 0);
                acc[mf][nf] = __builtin_amdgcn_mfma_f32_16x16x32_f16(
                    a2[mf], b2[nf], acc[mf][nf], 0, 0, 0);
            }
    }
    // epilogue -> g_G[ks][n][d] fp32
    #pragma unroll
    for (int mf = 0; mf < 4; ++mf) {
        const int nbase = n0 + wm*64 + mf*16 + (lane >> 4)*4;
        #pragma unroll
        for (int nf = 0; nf < 4; ++nf) {
            const int d = d0 + wn*64 + nf*16 + (lane & 15);
            #pragma unroll
            for (int j = 0; j < 4; ++j)
                g_G[ks][nbase + j][d] = acc[mf][nf][j];
        }
    }
}

// ---------------------------------------------------------------------------
// Epilogue: Gc = (Gr+i*Gi)*conj(e^{i alpha}) (|e^{ia}|=1, divide==conj-mult;
// rotation preserves row norm -> scale = 16/||G row||). Output = REAL part.
// ---------------------------------------------------------------------------
__global__ __launch_bounds__(256) void ker_fin(const float* __restrict__ pts,
                                               const float* __restrict__ A,
                                               float* __restrict__ out) {
    const int n = blockIdx.x;
    const int k = threadIdx.x;  // 0..255
    const float p0 = pts[(size_t)n*3], p1 = pts[(size_t)n*3+1], p2 = pts[(size_t)n*3+2];
    const float alp = p0*A[k] + p1*A[DH + k] + p2*A[2*DH + k];
    float sa, ca; fsincos(alp, &sa, &ca);
    const float Gr = g_G[0][n][k]      + g_G[1][n][k];
    const float Gi = g_G[0][n][DH + k] + g_G[1][n][DH + k];
    const float Re = Gr*ca + Gi*sa;
    float nr = Gr*Gr + Gi*Gi;
    #pragma unroll
    for (int off = 32; off > 0; off >>= 1) nr += __shfl_down(nr, off, 64);
    __shared__ float wsum[4];
    if ((k & 63) == 0) wsum[k >> 6] = nr;
    __syncthreads();
    const float total = wsum[0] + wsum[1] + wsum[2] + wsum[3];
    const float scale = 16.0f * rsqrtf(total);
    out[(size_t)n*DH + k] = Re * scale;
}

extern "C" void kernel_launch(void* const* d_in, const int* in_sizes, int n_in,
                              void* d_out, int out_size, void* d_ws, size_t ws_size,
                              hipStream_t stream) {
    const float* pts = (const float*)d_in[0];
    const float* A   = (const float*)d_in[1];
    const float* B   = (const float*)d_in[2];
    float* out = (float*)d_out;
    (void)d_ws; (void)ws_size; (void)out_size;

    ker_pre <<<256, 256, 0, stream>>>(pts, A);
    ker_T   <<<dim3(64, 2, 4), 512, 0, stream>>>(pts, B);
    ker_tsum<<<2048, 256, 0, stream>>>();
    ker_G   <<<dim3(128, 2, 2), 512, 0, stream>>>(pts, B);
    ker_fin <<<16384, 256, 0, stream>>>(pts, A, out);
}